// Round 1
// baseline (57.691 us; speedup 1.0000x reference)
//
#include <hip/hip_runtime.h>
#include <math.h>

#define NQ 9
#define HDIM 384
#define HOUT 128
#define WOUT 128
// W_MUL = sqrt(2)/sqrt(5) = sqrt(0.4)
#define W_MUL 0.6324555320336759f

// out[b,q,i,j] : (4, 9, 128, 128)
// z_q = A_q*sin(pi*x) + B_q*cos(pi*x)
//   A_q = sin(beta)sin(gamma)
//   B_q = cos(alpha)cos(gamma) - sin(alpha)cos(beta)sin(gamma)
// out[0] = z1*...*z8 ; out[q>=1] = z0*...*zq
__global__ __launch_bounds__(256) void quanconv_kernel(
    const float* __restrict__ x,      // (4,1,384,384)
    const float* __restrict__ w,      // (27,)
    float* __restrict__ out)          // (4,9,128,128)
{
    __shared__ float sA[NQ];
    __shared__ float sB[NQ];
    if (threadIdx.x < NQ) {
        int q = threadIdx.x;
        float al = w[3 * q + 0] * W_MUL;
        float be = w[3 * q + 1] * W_MUL;
        float ga = w[3 * q + 2] * W_MUL;
        float sa, ca, sb, cb, sg, cg;
        sincosf(al, &sa, &ca);
        sincosf(be, &sb, &cb);
        sincosf(ga, &sg, &cg);
        sA[q] = sb * sg;
        sB[q] = ca * cg - sa * cb * sg;
    }
    __syncthreads();

    int idx = blockIdx.x * blockDim.x + threadIdx.x;   // 0..65535
    int j = idx & (WOUT - 1);
    int i = (idx >> 7) & (HOUT - 1);
    int b = idx >> 14;

    const float* base = x + ((size_t)b * HDIM + 3 * i) * HDIM + 3 * j;

    float z[NQ];
#pragma unroll
    for (int di = 0; di < 3; ++di) {
#pragma unroll
        for (int dj = 0; dj < 3; ++dj) {
            float xv = base[di * HDIM + dj];
            float s, c;
            sincospif(xv, &s, &c);
            int q = di * 3 + dj;
            z[q] = sA[q] * s + sB[q] * c;
        }
    }

    float e[NQ];
    // prefix products z0*...*zq for q=1..8
    float p = z[0];
#pragma unroll
    for (int q = 1; q < NQ; ++q) { p *= z[q]; e[q] = p; }
    // suffix product z1*...*z8 for q=0
    float t = z[1];
#pragma unroll
    for (int q = 2; q < NQ; ++q) t *= z[q];
    e[0] = t;

    // out[b,q,i,j]
    size_t obase = (((size_t)b * NQ) * HOUT + i) * WOUT + j;
#pragma unroll
    for (int q = 0; q < NQ; ++q) {
        out[obase + (size_t)q * HOUT * WOUT] = e[q];
    }
}

extern "C" void kernel_launch(void* const* d_in, const int* in_sizes, int n_in,
                              void* d_out, int out_size, void* d_ws, size_t ws_size,
                              hipStream_t stream) {
    const float* x = (const float*)d_in[0];
    const float* w = (const float*)d_in[1];
    float* out = (float*)d_out;

    const int N = 4 * HOUT * WOUT;   // 65536 windows
    quanconv_kernel<<<N / 256, 256, 0, stream>>>(x, w, out);
}

// Round 2
// 56.794 us; speedup vs baseline: 1.0158x; 1.0158x over previous
//
#include <hip/hip_runtime.h>
#include <math.h>

#define NQ 9
#define HDIM 384
#define HOUT 128
#define WOUT 128
// W_MUL = sqrt(2)/sqrt(5) = sqrt(0.4)
#define W_MUL 0.6324555320336759f
// W_MUL / (2*pi): converts weight to revolutions for v_sin/v_cos
#define W_MUL_REV 0.10065842420897407f

// z_q = A_q*sin(pi*x) + B_q*cos(pi*x)
//   A_q = sin(beta)sin(gamma)
//   B_q = cos(alpha)cos(gamma) - sin(alpha)cos(beta)sin(gamma)
// out[b,0,i,j] = z1*...*z8 ; out[b,q>=1,i,j] = z0*...*zq
//
// Hardware trig: v_sin_f32(r) = sin(2*pi*r). sin(pi*x) = v_sin(0.5*x),
// x in [0,1) -> 0.5*x in [0,0.5): no range reduction needed.
__global__ __launch_bounds__(256) void quanconv_kernel(
    const float* __restrict__ x,      // (4,1,384,384)
    const float* __restrict__ w,      // (27,)
    float* __restrict__ out)          // (4,9,128,128)
{
    __shared__ float sA[NQ];
    __shared__ float sB[NQ];

    int idx = blockIdx.x * blockDim.x + threadIdx.x;   // 0..65535
    int j = idx & (WOUT - 1);
    int i = (idx >> 7) & (HOUT - 1);
    int b = idx >> 14;

    // Issue the 9 global loads FIRST so HBM latency hides under the
    // weight-trig + barrier below.
    const float* base = x + ((size_t)b * HDIM + 3 * i) * HDIM + 3 * j;
    float xv[NQ];
#pragma unroll
    for (int di = 0; di < 3; ++di)
#pragma unroll
        for (int dj = 0; dj < 3; ++dj)
            xv[di * 3 + dj] = base[di * HDIM + dj];

    if (threadIdx.x < NQ) {
        int q = threadIdx.x;
        // angles in REVOLUTIONS (w * W_MUL / 2pi), all in [0, 0.64]
        float al = w[3 * q + 0] * W_MUL_REV;
        float be = w[3 * q + 1] * W_MUL_REV;
        float ga = w[3 * q + 2] * W_MUL_REV;
        float sa = __builtin_amdgcn_sinf(al), ca = __builtin_amdgcn_cosf(al);
        float sb = __builtin_amdgcn_sinf(be), cb = __builtin_amdgcn_cosf(be);
        float sg = __builtin_amdgcn_sinf(ga), cg = __builtin_amdgcn_cosf(ga);
        sA[q] = sb * sg;
        sB[q] = ca * cg - sa * cb * sg;
    }
    __syncthreads();

    float z[NQ];
#pragma unroll
    for (int q = 0; q < NQ; ++q) {
        float r = 0.5f * xv[q];                       // revolutions, [0,0.5)
        float s = __builtin_amdgcn_sinf(r);
        float c = __builtin_amdgcn_cosf(r);
        z[q] = sA[q] * s + sB[q] * c;
    }

    float e[NQ];
    float p = z[0];
#pragma unroll
    for (int q = 1; q < NQ; ++q) { p *= z[q]; e[q] = p; }
    float t = z[1];
#pragma unroll
    for (int q = 2; q < NQ; ++q) t *= z[q];
    e[0] = t;

    size_t obase = (((size_t)b * NQ) * HOUT + i) * WOUT + j;
#pragma unroll
    for (int q = 0; q < NQ; ++q)
        out[obase + (size_t)q * HOUT * WOUT] = e[q];
}

extern "C" void kernel_launch(void* const* d_in, const int* in_sizes, int n_in,
                              void* d_out, int out_size, void* d_ws, size_t ws_size,
                              hipStream_t stream) {
    const float* x = (const float*)d_in[0];
    const float* w = (const float*)d_in[1];
    float* out = (float*)d_out;

    const int N = 4 * HOUT * WOUT;   // 65536 windows
    quanconv_kernel<<<N / 256, 256, 0, stream>>>(x, w, out);
}